// Round 11
// baseline (1004.845 us; speedup 1.0000x reference)
//
#include <hip/hip_runtime.h>
#include <hip/hip_cooperative_groups.h>
#include <hip/hip_fp8.h>
#include <math.h>

namespace cg = cooperative_groups;

#define BATCH   2048
#define NROWS   4096   // 2*BATCH
#define LATENT  2048
#define PROJ    256
#define BN_EPS  1e-5f
#define COS_EPS 1e-8f
#define W1SCALE 32.0f      // W1/W2 pre-scaled into e4m3 normal range
#define W1INV   (1.0f / 32.0f)
#define ZNSCALE 16.0f      // zn components ~N(0,1/16) -> x16 for e4m3
#define SIMSCALE (1.0f / 128.0f)   // s = dotq/128 (16*16 scale / temp 0.5)

typedef float f32x4 __attribute__((ext_vector_type(4)));
typedef long  i64;

__device__ __forceinline__ unsigned short f2bf(float f) {
    union { float f; unsigned int u; } c; c.f = f;
    return (unsigned short)((c.u + 0x7FFFu + ((c.u >> 16) & 1u)) >> 16);
}
__device__ __forceinline__ float bf2f(unsigned short h) {
    union { unsigned int u; float f; } c; c.u = ((unsigned int)h) << 16;
    return c.f;
}
__device__ __forceinline__ unsigned char f2fp8(float f) {
    __hip_fp8_e4m3 t(f);
    return (unsigned char)t.__x;
}
__device__ __forceinline__ float fp82f(unsigned char b) {
    __hip_fp8_e4m3 t; t.__x = b;
    return (float)t;
}
__device__ __forceinline__ void gl_lds16(const void* g, void* l) {
    __builtin_amdgcn_global_load_lds(
        (const __attribute__((address_space(1))) void*)g,
        (__attribute__((address_space(3))) void*)l, 16, 0, 0);
}
__device__ __forceinline__ int mix8(int R) {
    return (R & 7) ^ ((R >> 1) & 4);
}

struct Params {
    const float *h_i, *h_j, *W1, *gamma, *beta, *W2, *b2;
    float *out;
    float *sums, *sumsqs, *rowsum, *dgA, *posA;
    unsigned char *Hq, *W1q, *W2q, *Xq, *ZNq;
    unsigned short *Zpb;
};

#define G1 1048576
#define G2 2097152
#define G3 3145728
#define G4 3276800

// ---------------------------------------------------------------------------
// shared phase bodies (identical math to R10 kernels)
// ---------------------------------------------------------------------------
__device__ __forceinline__ void dev_cvt(int i, const Params& p) {
    if (i < G2) {
        const float* src = (i < G1) ? p.h_i : p.h_j;
        int off = (i < G1) ? i : i - G1;
        float4 v = reinterpret_cast<const float4*>(src)[off];
        uchar4 o;
        o.x = f2fp8(v.x); o.y = f2fp8(v.y); o.z = f2fp8(v.z); o.w = f2fp8(v.w);
        reinterpret_cast<uchar4*>(p.Hq)[i] = o;
    } else if (i < G3) {
        int off = i - G2;
        float4 v = reinterpret_cast<const float4*>(p.W1)[off];
        uchar4 o;
        o.x = f2fp8(v.x * W1SCALE); o.y = f2fp8(v.y * W1SCALE);
        o.z = f2fp8(v.z * W1SCALE); o.w = f2fp8(v.w * W1SCALE);
        reinterpret_cast<uchar4*>(p.W1q)[off] = o;
    } else {
        int off = i - G3;
        float4 v = reinterpret_cast<const float4*>(p.W2)[off];
        uchar4 o;
        o.x = f2fp8(v.x * W1SCALE); o.y = f2fp8(v.y * W1SCALE);
        o.z = f2fp8(v.z * W1SCALE); o.w = f2fp8(v.w * W1SCALE);
        reinterpret_cast<uchar4*>(p.W2q)[off] = o;
    }
}

// fp8 MFMA K-loop: BM=128, BN=64, BK=128. acc[4][2]. 4 waves in 2x2.
template<int KSTRIDE, int KLEN>
__device__ __forceinline__ void fp8_loop(
    const unsigned char* __restrict__ Ab, const unsigned char* __restrict__ Bb,
    unsigned char* As, unsigned char* Bs, f32x4 acc[4][2], int tid)
{
    const int wid = tid >> 6, lane = tid & 63;
    const int mblk = (wid >> 1) * 64, nblk = (wid & 1) * 32;
    const int lr = lane & 15, lk = lane >> 4;
    for (int k0 = 0; k0 < KLEN; k0 += 128) {
        __syncthreads();
        #pragma unroll
        for (int u = 0; u < 4; ++u) {
            int li = u * 256 + tid;
            int r = li >> 3, s = li & 7;
            gl_lds16(Ab + (size_t)r * KSTRIDE + k0 + ((s ^ mix8(r)) * 16), As + li * 16);
        }
        #pragma unroll
        for (int u = 0; u < 2; ++u) {
            int li = u * 256 + tid;
            int r = li >> 3, s = li & 7;
            gl_lds16(Bb + (size_t)r * KSTRIDE + k0 + ((s ^ mix8(r)) * 16), Bs + li * 16);
        }
        __syncthreads();
        i64 af[4][4], bv[2][4];
        #pragma unroll
        for (int i = 0; i < 4; ++i) {
            int R = mblk + i * 16 + lr;
            int mr = mix8(R);
            int base = R * 128 + (lk & 1) * 8;
            #pragma unroll
            for (int t = 0; t < 4; ++t) {
                int g = 2 * t + (lk >> 1);
                af[i][t] = *reinterpret_cast<const i64*>(As + base + ((g ^ mr) << 4));
            }
        }
        #pragma unroll
        for (int j = 0; j < 2; ++j) {
            int R = nblk + j * 16 + lr;
            int mr = mix8(R);
            int base = R * 128 + (lk & 1) * 8;
            #pragma unroll
            for (int t = 0; t < 4; ++t) {
                int g = 2 * t + (lk >> 1);
                bv[j][t] = *reinterpret_cast<const i64*>(Bs + base + ((g ^ mr) << 4));
            }
        }
        #pragma unroll
        for (int t = 0; t < 4; ++t)
            #pragma unroll
            for (int i = 0; i < 4; ++i)
                #pragma unroll
                for (int j = 0; j < 2; ++j)
                    acc[i][j] = __builtin_amdgcn_mfma_f32_16x16x32_fp8_fp8(
                        af[i][t], bv[j][t], acc[i][j], 0, 0, 0);
    }
}

__device__ __forceinline__ void dev_gemm1_tile(
    int m0, int n0, unsigned char* As, unsigned char* Bs, int tid, const Params& p)
{
    f32x4 zero = {0.f, 0.f, 0.f, 0.f};
    f32x4 acc[4][2];
    #pragma unroll
    for (int i = 0; i < 4; ++i) { acc[i][0] = zero; acc[i][1] = zero; }
    fp8_loop<LATENT, LATENT>(p.Hq + (size_t)m0 * LATENT, p.W1q + (size_t)n0 * LATENT,
                             As, Bs, acc, tid);
    const int wid = tid >> 6, lane = tid & 63;
    const int mblk = (wid >> 1) * 64, nblk = (wid & 1) * 32;
    const int lr = lane & 15, lq = lane >> 4;
    const int half = m0 >> 11;
    #pragma unroll
    for (int j = 0; j < 2; ++j) {
        float s = 0.f, q = 0.f;
        #pragma unroll
        for (int i = 0; i < 4; ++i)
            #pragma unroll
            for (int r = 0; r < 4; ++r) {
                float v = acc[i][j][r] * W1INV;
                s += v; q += v * v;
                int row = m0 + mblk + i * 16 + lq * 4 + r;
                int col = n0 + nblk + j * 16 + lr;
                p.Xq[(size_t)row * LATENT + col] = f2fp8(v);   // raw X, ~N(0,1)
            }
        s += __shfl_xor(s, 16, 64);  q += __shfl_xor(q, 16, 64);
        s += __shfl_xor(s, 32, 64);  q += __shfl_xor(q, 32, 64);
        if (lq == 0) {
            int col = n0 + nblk + j * 16 + lr;
            atomicAdd(&p.sums[half * LATENT + col], s);
            atomicAdd(&p.sumsqs[half * LATENT + col], q);
        }
    }
}

__device__ __forceinline__ void dev_bnrelu(int g, const Params& p) {
    int row = g >> 8;               // 256 groups of 8 per row
    int col = (g & 255) * 8;
    int half = row >> 11;
    size_t idx = (size_t)row * LATENT + col;
    uchar4 a = *reinterpret_cast<const uchar4*>(p.Xq + idx);
    uchar4 b = *reinterpret_cast<const uchar4*>(p.Xq + idx + 4);
    uchar4 oa, ob;
    #pragma unroll
    for (int u = 0; u < 8; ++u) {
        int c = col + u;
        int gi = half * LATENT + c;
        float mu  = p.sums[gi] * (1.0f / BATCH);
        float var = p.sumsqs[gi] * (1.0f / BATCH) - mu * mu;
        float sc = p.gamma[c] * rsqrtf(var + BN_EPS);
        float sh = p.beta[c] - mu * sc;
        unsigned char x = (u < 4) ? ((const unsigned char*)&a)[u] : ((const unsigned char*)&b)[u - 4];
        unsigned char o = f2fp8(fmaxf(fmaf(fp82f(x), sc, sh), 0.f));
        if (u < 4) ((unsigned char*)&oa)[u] = o; else ((unsigned char*)&ob)[u - 4] = o;
    }
    *reinterpret_cast<uchar4*>(p.Xq + idx) = oa;
    *reinterpret_cast<uchar4*>(p.Xq + idx + 4) = ob;
}

__device__ __forceinline__ void dev_gemm2_tile(
    int kc, int m0, int n0, unsigned char* As, unsigned char* Bs, int tid, const Params& p)
{
    f32x4 zero = {0.f, 0.f, 0.f, 0.f};
    f32x4 acc[4][2];
    #pragma unroll
    for (int i = 0; i < 4; ++i) { acc[i][0] = zero; acc[i][1] = zero; }
    fp8_loop<LATENT, 512>(p.Xq + (size_t)m0 * LATENT + kc * 512,
                          p.W2q + (size_t)n0 * LATENT + kc * 512, As, Bs, acc, tid);
    unsigned short* Zk = p.Zpb + (size_t)kc * NROWS * PROJ;
    const int wid = tid >> 6, lane = tid & 63;
    const int mblk = (wid >> 1) * 64, nblk = (wid & 1) * 32;
    const int lr = lane & 15, lq = lane >> 4;
    #pragma unroll
    for (int i = 0; i < 4; ++i)
        #pragma unroll
        for (int j = 0; j < 2; ++j)
            #pragma unroll
            for (int r = 0; r < 4; ++r) {
                int row = m0 + mblk + i * 16 + lq * 4 + r;
                int col = n0 + nblk + j * 16 + lr;
                Zk[(size_t)row * PROJ + col] = f2bf(acc[i][j][r] * W1INV);
            }
}

__device__ __forceinline__ void dev_rownorm(int row, int lane, const Params& p) {
    float v[4];
    float sq = 0.f;
    #pragma unroll
    for (int i = 0; i < 4; ++i) {
        int col = lane + i * 64;
        float t = p.b2[col];
        #pragma unroll
        for (int c = 0; c < 4; ++c)
            t += bf2f(p.Zpb[(size_t)c * NROWS * PROJ + (size_t)row * PROJ + col]);
        v[i] = t;
        sq += t * t;
    }
    #pragma unroll
    for (int off = 32; off > 0; off >>= 1) sq += __shfl_xor(sq, off, 64);
    float inv = ZNSCALE / fmaxf(sqrtf(sq), COS_EPS);
    #pragma unroll
    for (int i = 0; i < 4; ++i)
        p.ZNq[(size_t)row * PROJ + lane + i * 64] = f2fp8(v[i] * inv);
}

// one 128x128 sim tile (upper triangle); K=256 staged in one shot.
__device__ __forceinline__ void dev_simlse_tile(
    int r0, int j0, unsigned char* As, unsigned char* Bs, int tid, const Params& p)
{
    const bool offdiag = (j0 != r0);
    const unsigned char* Ab = p.ZNq + (size_t)r0 * PROJ;
    const unsigned char* Bb = p.ZNq + (size_t)j0 * PROJ;
    __syncthreads();   // prior LDS reads (previous tile / phase) complete
    #pragma unroll
    for (int u = 0; u < 8; ++u) {
        int li = u * 256 + tid;
        int r = li >> 4, s = li & 15;
        gl_lds16(Ab + (size_t)r * PROJ + ((s ^ (r & 15)) * 16), As + li * 16);
    }
    #pragma unroll
    for (int u = 0; u < 8; ++u) {
        int li = u * 256 + tid;
        int r = li >> 4, s = li & 15;
        gl_lds16(Bb + (size_t)r * PROJ + ((s ^ (r & 15)) * 16), Bs + li * 16);
    }
    __syncthreads();
    const int wid = tid >> 6, lane = tid & 63;
    const int mblk = (wid >> 1) * 64, nblk = (wid & 1) * 64;
    const int lr = lane & 15, lk = lane >> 4;
    f32x4 zero = {0.f, 0.f, 0.f, 0.f};
    f32x4 acc[4][4];
    #pragma unroll
    for (int i = 0; i < 4; ++i)
        #pragma unroll
        for (int j = 0; j < 4; ++j) acc[i][j] = zero;
    #pragma unroll
    for (int t = 0; t < 8; ++t) {
        int g = 2 * t + (lk >> 1);
        i64 af[4], bv[4];
        #pragma unroll
        for (int i = 0; i < 4; ++i) {
            int R = mblk + i * 16 + lr;
            af[i] = *reinterpret_cast<const i64*>(As + R * 256 + ((g ^ (R & 15)) << 4) + (lk & 1) * 8);
        }
        #pragma unroll
        for (int j = 0; j < 4; ++j) {
            int R = nblk + j * 16 + lr;
            bv[j] = *reinterpret_cast<const i64*>(Bs + R * 256 + ((g ^ (R & 15)) << 4) + (lk & 1) * 8);
        }
        #pragma unroll
        for (int i = 0; i < 4; ++i)
            #pragma unroll
            for (int j = 0; j < 4; ++j)
                acc[i][j] = __builtin_amdgcn_mfma_f32_16x16x32_fp8_fp8(af[i], bv[j], acc[i][j], 0, 0, 0);
    }
    const int lq = lane >> 4;
    float tcol[4] = {0.f, 0.f, 0.f, 0.f};
    #pragma unroll
    for (int i = 0; i < 4; ++i)
        #pragma unroll
        for (int r = 0; r < 4; ++r) {
            int R = r0 + mblk + i * 16 + lq * 4 + r;
            int P = (R < BATCH) ? R + BATCH : R - BATCH;
            float t = 0.f;
            #pragma unroll
            for (int j = 0; j < 4; ++j) {
                int J = j0 + nblk + j * 16 + lr;
                float s = acc[i][j][r] * SIMSCALE;
                float e = __expf(s);
                t += e;
                tcol[j] += e;
                if (J == R) p.dgA[R] = e;
                if (J == P) { p.posA[R] = s; p.posA[J] = s; }
            }
            t += __shfl_xor(t, 1, 64);
            t += __shfl_xor(t, 2, 64);
            t += __shfl_xor(t, 4, 64);
            t += __shfl_xor(t, 8, 64);
            if (lr == 0) atomicAdd(&p.rowsum[R], t);
        }
    if (offdiag) {
        #pragma unroll
        for (int j = 0; j < 4; ++j) {
            float c = tcol[j];
            c += __shfl_xor(c, 16, 64);
            c += __shfl_xor(c, 32, 64);
            if (lq == 0) atomicAdd(&p.rowsum[j0 + nblk + j * 16 + lr], c);
        }
    }
}

// ---------------------------------------------------------------------------
// Fused cooperative kernel: 512 blocks x 256 threads, 64 KB LDS (2 blocks/CU).
// ---------------------------------------------------------------------------
__global__ __launch_bounds__(256) void simclr_fused(Params p)
{
    cg::grid_group grid = cg::this_grid();
    __shared__ __align__(16) unsigned char smem[65536];
    const int tid = threadIdx.x;
    const int b = blockIdx.x;

    // phase 0: convert inputs + zero accumulators
    if (b == 0) {
        #pragma unroll
        for (int u = 0; u < 48; ++u) p.sums[u * 256 + tid] = 0.f;   // sums|sumsqs|rowsum
    }
    for (int i = b * 256 + tid; i < G4; i += 512 * 256) dev_cvt(i, p);
    __threadfence(); grid.sync(); __threadfence();

    // phase 1: gemm1 (1024 tiles, 2 per block)
    {
        unsigned char* As = smem;
        unsigned char* Bs = smem + 16384;
        for (int tt = 0; tt < 2; ++tt) {
            int t = b + tt * 512;
            dev_gemm1_tile((t >> 5) * 128, (t & 31) * 64, As, Bs, tid, p);
        }
    }
    __threadfence(); grid.sync(); __threadfence();

    // phase 2: BN+ReLU in-place on fp8 X
    for (int g = b * 256 + tid; g < NROWS * LATENT / 8; g += 512 * 256) dev_bnrelu(g, p);
    __threadfence(); grid.sync(); __threadfence();

    // phase 3: gemm2 split-K=4 (512 tiles, 1 per block)
    {
        unsigned char* As = smem;
        unsigned char* Bs = smem + 16384;
        int kc = b >> 7, r = b & 127;
        dev_gemm2_tile(kc, (r >> 2) * 128, (r & 3) * 64, As, Bs, tid, p);
    }
    __threadfence(); grid.sync(); __threadfence();

    // phase 4: rownorm (2 rows per wave)
    {
        int w = b * 4 + (tid >> 6);
        dev_rownorm(w, tid & 63, p);
        dev_rownorm(w + 2048, tid & 63, p);
    }
    __threadfence(); grid.sync(); __threadfence();

    // phase 5: simlse upper-triangle tiles (528 over 512 blocks)
    {
        unsigned char* As = smem;
        unsigned char* Bs = smem + 32768;
        for (int t = b; t < 528; t += 512) {
            int ti = 0, rem = t;
            while (rem >= 32 - ti) { rem -= (32 - ti); ++ti; }
            dev_simlse_tile(ti * 128, (ti + rem) * 128, As, Bs, tid, p);
        }
    }
    __threadfence(); grid.sync(); __threadfence();

    // phase 6: loss reduction (block 0)
    if (b == 0) {
        float* red = (float*)smem;
        float s = 0.f;
        for (int r = tid; r < NROWS; r += 256)
            s += logf(p.rowsum[r] - p.dgA[r]) - p.posA[r];
        red[tid] = s;
        __syncthreads();
        for (int off = 128; off > 0; off >>= 1) {
            if (tid < off) red[tid] += red[tid + off];
            __syncthreads();
        }
        if (tid == 0) p.out[0] = red[0] * (1.0f / NROWS);
    }
}

// ---------------------------------------------------------------------------
// Fallback kernels (R10 path) in case cooperative launch is rejected.
// ---------------------------------------------------------------------------
__global__ __launch_bounds__(256) void fb_cvt(Params p) {
    int i = blockIdx.x * 256 + threadIdx.x;
    if (blockIdx.x == 0) {
        #pragma unroll
        for (int u = 0; u < 48; ++u) p.sums[u * 256 + threadIdx.x] = 0.f;
    }
    if (i < G4) dev_cvt(i, p);
}
__global__ __launch_bounds__(256) void fb_gemm1(Params p) {
    __shared__ __align__(16) unsigned char As[128 * 128];
    __shared__ __align__(16) unsigned char Bs[64 * 128];
    dev_gemm1_tile(blockIdx.y * 128, blockIdx.x * 64, As, Bs, threadIdx.x, p);
}
__global__ __launch_bounds__(256) void fb_bnrelu(Params p) {
    dev_bnrelu(blockIdx.x * 256 + threadIdx.x, p);
}
__global__ __launch_bounds__(256) void fb_gemm2(Params p) {
    __shared__ __align__(16) unsigned char As[128 * 128];
    __shared__ __align__(16) unsigned char Bs[64 * 128];
    dev_gemm2_tile(blockIdx.z, blockIdx.y * 128, blockIdx.x * 64, As, Bs, threadIdx.x, p);
}
__global__ __launch_bounds__(256) void fb_rownorm(Params p) {
    dev_rownorm(blockIdx.x * 4 + (threadIdx.x >> 6), threadIdx.x & 63, p);
}
__global__ __launch_bounds__(256) void fb_simlse(Params p) {
    if (blockIdx.x < blockIdx.y) return;
    __shared__ __align__(16) unsigned char As[128 * 256];
    __shared__ __align__(16) unsigned char Bs[128 * 256];
    dev_simlse_tile(blockIdx.y * 128, blockIdx.x * 128, As, Bs, threadIdx.x, p);
}
__global__ __launch_bounds__(256) void fb_loss(Params p) {
    __shared__ float red[256];
    float s = 0.f;
    for (int r = threadIdx.x; r < NROWS; r += 256)
        s += logf(p.rowsum[r] - p.dgA[r]) - p.posA[r];
    red[threadIdx.x] = s;
    __syncthreads();
    for (int off = 128; off > 0; off >>= 1) {
        if (threadIdx.x < off) red[threadIdx.x] += red[threadIdx.x + off];
        __syncthreads();
    }
    if (threadIdx.x == 0) p.out[0] = red[0] * (1.0f / NROWS);
}

// ---------------------------------------------------------------------------
extern "C" void kernel_launch(void* const* d_in, const int* in_sizes, int n_in,
                              void* d_out, int out_size, void* d_ws, size_t ws_size,
                              hipStream_t stream)
{
    Params p;
    p.h_i   = (const float*)d_in[0];
    p.h_j   = (const float*)d_in[1];
    p.W1    = (const float*)d_in[2];
    p.gamma = (const float*)d_in[3];
    p.beta  = (const float*)d_in[4];
    p.W2    = (const float*)d_in[5];
    p.b2    = (const float*)d_in[6];
    p.out   = (float*)d_out;

    unsigned short* Zpb = (unsigned short*)d_ws;             // 4 * 4096*256 bf16
    p.Zpb    = Zpb;
    p.sums   = (float*)(Zpb + (size_t)4 * NROWS * PROJ);     // 4096
    p.sumsqs = p.sums + 2 * LATENT;                          // 4096
    p.rowsum = p.sumsqs + 2 * LATENT;                        // 4096
    p.dgA    = p.rowsum + NROWS;                             // 4096
    p.posA   = p.dgA + NROWS;                                // 4096
    p.Hq     = (unsigned char*)(p.posA + NROWS);             // 4096*2048 fp8
    p.W1q    = p.Hq + (size_t)NROWS * LATENT;                // 2048*2048 fp8
    p.W2q    = p.W1q + (size_t)LATENT * LATENT;              // 256*2048 fp8
    p.Xq     = p.W2q + (size_t)PROJ * LATENT;                // 4096*2048 fp8
    p.ZNq    = p.Xq + (size_t)NROWS * LATENT;                // 4096*256 fp8

    void* args[] = { &p };
    hipError_t err = hipLaunchCooperativeKernel(
        (const void*)simclr_fused, dim3(512), dim3(256), args, 0, stream);
    if (err != hipSuccess) {
        // fallback: proven multi-launch path (identical math)
        fb_cvt<<<(G4 + 255) / 256, 256, 0, stream>>>(p);
        fb_gemm1<<<dim3(LATENT / 64, NROWS / 128), 256, 0, stream>>>(p);
        fb_bnrelu<<<NROWS, 256, 0, stream>>>(p);
        fb_gemm2<<<dim3(PROJ / 64, NROWS / 128, 4), 256, 0, stream>>>(p);
        fb_rownorm<<<NROWS / 4, 256, 0, stream>>>(p);
        fb_simlse<<<dim3(NROWS / 128, NROWS / 128), 256, 0, stream>>>(p);
        fb_loss<<<1, 256, 0, stream>>>(p);
    }
}

// Round 12
// 202.328 us; speedup vs baseline: 4.9664x; 4.9664x over previous
//
#include <hip/hip_runtime.h>
#include <hip/hip_fp8.h>
#include <math.h>

#define BATCH   2048
#define NROWS   4096   // 2*BATCH
#define LATENT  2048
#define PROJ    256
#define BN_EPS  1e-5f
#define COS_EPS 1e-8f
#define W1SCALE 32.0f      // W1/W2 pre-scaled into e4m3 normal range
#define W1INV   (1.0f / 32.0f)
#define ZNSCALE 16.0f      // zn components ~N(0,1/16) -> x16 for e4m3
#define SIMSCALE (1.0f / 128.0f)   // s = dotq/128 (16*16 scale / temp 0.5)

typedef float f32x4 __attribute__((ext_vector_type(4)));
typedef long  i64;

__device__ __forceinline__ unsigned char f2fp8(float f) {
    __hip_fp8_e4m3 t(f);
    return (unsigned char)t.__x;
}
__device__ __forceinline__ float fp82f(unsigned char b) {
    __hip_fp8_e4m3 t; t.__x = b;
    return (float)t;
}
__device__ __forceinline__ void gl_lds16(const void* g, void* l) {
    __builtin_amdgcn_global_load_lds(
        (const __attribute__((address_space(1))) void*)g,
        (__attribute__((address_space(3))) void*)l, 16, 0, 0);
}
__device__ __forceinline__ int mix8(int R) {
    return (R & 7) ^ ((R >> 1) & 4);
}

// ---------------------------------------------------------------------------
// Fused convert: h_i,h_j -> fp8 Hq; W1 -> fp8*32 W1q; W2 -> fp8*32 W2q.
// Block 0 zeroes the atomic accumulators (sums|sumsqs|rowsum = 12288 floats).
// ---------------------------------------------------------------------------
#define G1 1048576
#define G2 2097152
#define G3 3145728
#define G4 3276800
__global__ __launch_bounds__(256) void cvt_all_kernel(
    const float* __restrict__ h_i, const float* __restrict__ h_j,
    const float* __restrict__ W1,  const float* __restrict__ W2,
    unsigned char* __restrict__ Hq, unsigned char* __restrict__ W1q,
    unsigned char* __restrict__ W2q, float* __restrict__ zeroacc)
{
    int i = blockIdx.x * 256 + threadIdx.x;
    if (blockIdx.x == 0) {
        #pragma unroll
        for (int u = 0; u < 48; ++u) zeroacc[u * 256 + threadIdx.x] = 0.f;
    }
    if (i >= G4) return;
    if (i < G2) {
        const float* src = (i < G1) ? h_i : h_j;
        int off = (i < G1) ? i : i - G1;
        float4 v = reinterpret_cast<const float4*>(src)[off];
        uchar4 o;
        o.x = f2fp8(v.x); o.y = f2fp8(v.y); o.z = f2fp8(v.z); o.w = f2fp8(v.w);
        reinterpret_cast<uchar4*>(Hq)[i] = o;
    } else if (i < G3) {
        int off = i - G2;
        float4 v = reinterpret_cast<const float4*>(W1)[off];
        uchar4 o;
        o.x = f2fp8(v.x * W1SCALE); o.y = f2fp8(v.y * W1SCALE);
        o.z = f2fp8(v.z * W1SCALE); o.w = f2fp8(v.w * W1SCALE);
        reinterpret_cast<uchar4*>(W1q)[off] = o;
    } else {
        int off = i - G3;
        float4 v = reinterpret_cast<const float4*>(W2)[off];
        uchar4 o;
        o.x = f2fp8(v.x * W1SCALE); o.y = f2fp8(v.y * W1SCALE);
        o.z = f2fp8(v.z * W1SCALE); o.w = f2fp8(v.w * W1SCALE);
        reinterpret_cast<uchar4*>(W2q)[off] = o;
    }
}

// ---------------------------------------------------------------------------
// fp8 MFMA K-loop: BM=128, BN=64, BK=128. acc[4][2]. 4 waves in 2x2.
// ---------------------------------------------------------------------------
template<int KSTRIDE, int KLEN>
__device__ __forceinline__ void fp8_loop(
    const unsigned char* __restrict__ Ab, const unsigned char* __restrict__ Bb,
    unsigned char* As, unsigned char* Bs, f32x4 acc[4][2], int tid)
{
    const int wid = tid >> 6, lane = tid & 63;
    const int mblk = (wid >> 1) * 64, nblk = (wid & 1) * 32;
    const int lr = lane & 15, lk = lane >> 4;
    for (int k0 = 0; k0 < KLEN; k0 += 128) {
        __syncthreads();
        #pragma unroll
        for (int u = 0; u < 4; ++u) {
            int li = u * 256 + tid;
            int r = li >> 3, s = li & 7;
            gl_lds16(Ab + (size_t)r * KSTRIDE + k0 + ((s ^ mix8(r)) * 16), As + li * 16);
        }
        #pragma unroll
        for (int u = 0; u < 2; ++u) {
            int li = u * 256 + tid;
            int r = li >> 3, s = li & 7;
            gl_lds16(Bb + (size_t)r * KSTRIDE + k0 + ((s ^ mix8(r)) * 16), Bs + li * 16);
        }
        __syncthreads();
        i64 af[4][4], bv[2][4];
        #pragma unroll
        for (int i = 0; i < 4; ++i) {
            int R = mblk + i * 16 + lr;
            int mr = mix8(R);
            int base = R * 128 + (lk & 1) * 8;
            #pragma unroll
            for (int t = 0; t < 4; ++t) {
                int g = 2 * t + (lk >> 1);
                af[i][t] = *reinterpret_cast<const i64*>(As + base + ((g ^ mr) << 4));
            }
        }
        #pragma unroll
        for (int j = 0; j < 2; ++j) {
            int R = nblk + j * 16 + lr;
            int mr = mix8(R);
            int base = R * 128 + (lk & 1) * 8;
            #pragma unroll
            for (int t = 0; t < 4; ++t) {
                int g = 2 * t + (lk >> 1);
                bv[j][t] = *reinterpret_cast<const i64*>(Bs + base + ((g ^ mr) << 4));
            }
        }
        #pragma unroll
        for (int t = 0; t < 4; ++t)
            #pragma unroll
            for (int i = 0; i < 4; ++i)
                #pragma unroll
                for (int j = 0; j < 2; ++j)
                    acc[i][j] = __builtin_amdgcn_mfma_f32_16x16x32_fp8_fp8(
                        af[i][t], bv[j][t], acc[i][j], 0, 0, 0);
    }
}

// ---------------------------------------------------------------------------
// GEMM1 (fp8): X[m][n] = sum_k H[m][k]*W1[n][k]  (4096x2048x2048)
// BM=128 x BN=64 -> 1024 blocks (4/CU). Epilogue: raw-X fp8 store + BN stats.
// ---------------------------------------------------------------------------
__global__ __launch_bounds__(256, 4) void gemm1_fp8(
    const unsigned char* __restrict__ Hq, const unsigned char* __restrict__ W1q,
    unsigned char* __restrict__ Xq, float* __restrict__ sums, float* __restrict__ sumsqs)
{
    __shared__ __align__(16) unsigned char As[128 * 128];
    __shared__ __align__(16) unsigned char Bs[64 * 128];
    const int tid = threadIdx.x;
    const int m0 = blockIdx.y * 128, n0 = blockIdx.x * 64;
    f32x4 zero = {0.f, 0.f, 0.f, 0.f};
    f32x4 acc[4][2];
    #pragma unroll
    for (int i = 0; i < 4; ++i) { acc[i][0] = zero; acc[i][1] = zero; }
    fp8_loop<LATENT, LATENT>(Hq + (size_t)m0 * LATENT, W1q + (size_t)n0 * LATENT,
                             As, Bs, acc, tid);
    const int wid = tid >> 6, lane = tid & 63;
    const int mblk = (wid >> 1) * 64, nblk = (wid & 1) * 32;
    const int lr = lane & 15, lq = lane >> 4;
    const int half = m0 >> 11;
    #pragma unroll
    for (int j = 0; j < 2; ++j) {
        float s = 0.f, q = 0.f;
        #pragma unroll
        for (int i = 0; i < 4; ++i)
            #pragma unroll
            for (int r = 0; r < 4; ++r) {
                float v = acc[i][j][r] * W1INV;
                s += v; q += v * v;
                int row = m0 + mblk + i * 16 + lq * 4 + r;
                int col = n0 + nblk + j * 16 + lr;
                Xq[(size_t)row * LATENT + col] = f2fp8(v);   // raw X, ~N(0,1)
            }
        s += __shfl_xor(s, 16, 64);  q += __shfl_xor(q, 16, 64);
        s += __shfl_xor(s, 32, 64);  q += __shfl_xor(q, 32, 64);
        if (lq == 0) {
            int col = n0 + nblk + j * 16 + lr;
            atomicAdd(&sums[half * LATENT + col], s);
            atomicAdd(&sumsqs[half * LATENT + col], q);
        }
    }
}

// ---------------------------------------------------------------------------
// BN+ReLU in-place on fp8 X. One block per row, 8 elems/thread.
// ---------------------------------------------------------------------------
__global__ __launch_bounds__(256) void bnrelu8_kernel(
    unsigned char* __restrict__ Xq, const float* __restrict__ sums,
    const float* __restrict__ sumsqs, const float* __restrict__ gamma,
    const float* __restrict__ beta)
{
    const int row = blockIdx.x;
    const int half = row >> 11;
    const int col = threadIdx.x * 8;
    size_t idx = (size_t)row * LATENT + col;
    uchar4 a = *reinterpret_cast<const uchar4*>(Xq + idx);
    uchar4 b = *reinterpret_cast<const uchar4*>(Xq + idx + 4);
    uchar4 oa, ob;
    #pragma unroll
    for (int u = 0; u < 8; ++u) {
        int c = col + u;
        int g = half * LATENT + c;
        float mu  = sums[g] * (1.0f / BATCH);
        float var = sumsqs[g] * (1.0f / BATCH) - mu * mu;
        float sc = gamma[c] * rsqrtf(var + BN_EPS);
        float sh = beta[c] - mu * sc;
        unsigned char x = (u < 4) ? ((const unsigned char*)&a)[u] : ((const unsigned char*)&b)[u - 4];
        unsigned char o = f2fp8(fmaxf(fmaf(fp82f(x), sc, sh), 0.f));
        if (u < 4) ((unsigned char*)&oa)[u] = o; else ((unsigned char*)&ob)[u - 4] = o;
    }
    *reinterpret_cast<uchar4*>(Xq + idx) = oa;
    *reinterpret_cast<uchar4*>(Xq + idx + 4) = ob;
}

// ---------------------------------------------------------------------------
// GEMM2 + rownorm fused: BM=128 x BN=256 (full PROJ) x K=2048 -> 32 blocks.
// Each block owns complete Z rows: z = acc/32 + b2 (fp32), per-row L2 norm
// (lr-butterfly + 2-wave LDS combine), write fp8 ZNq = fp8(z * 16 / ||z||).
// LDS: A 16KB + B 32KB + red 1KB.
// ---------------------------------------------------------------------------
__global__ __launch_bounds__(256) void gemm2rn_fp8(
    const unsigned char* __restrict__ Xq, const unsigned char* __restrict__ W2q,
    const float* __restrict__ b2, unsigned char* __restrict__ ZNq)
{
    __shared__ __align__(16) unsigned char As[128 * 128];
    __shared__ __align__(16) unsigned char Bs[256 * 128];
    __shared__ float red[128][2];
    const int tid = threadIdx.x;
    const int m0 = blockIdx.x * 128;
    const unsigned char* Ab = Xq + (size_t)m0 * LATENT;
    const int wid = tid >> 6, lane = tid & 63;
    const int mblk = (wid >> 1) * 64, nblk = (wid & 1) * 128;
    const int lr = lane & 15, lk = lane >> 4;
    f32x4 zero = {0.f, 0.f, 0.f, 0.f};
    f32x4 acc[4][8];
    #pragma unroll
    for (int i = 0; i < 4; ++i)
        #pragma unroll
        for (int j = 0; j < 8; ++j) acc[i][j] = zero;

    for (int k0 = 0; k0 < LATENT; k0 += 128) {
        __syncthreads();
        #pragma unroll
        for (int u = 0; u < 4; ++u) {
            int li = u * 256 + tid;
            int r = li >> 3, s = li & 7;
            gl_lds16(Ab + (size_t)r * LATENT + k0 + ((s ^ mix8(r)) * 16), As + li * 16);
        }
        #pragma unroll
        for (int u = 0; u < 8; ++u) {
            int li = u * 256 + tid;
            int r = li >> 3, s = li & 7;
            gl_lds16(W2q + (size_t)r * LATENT + k0 + ((s ^ mix8(r)) * 16), Bs + li * 16);
        }
        __syncthreads();
        #pragma unroll
        for (int t = 0; t < 4; ++t) {
            int g = 2 * t + (lk >> 1);
            i64 af[4], bv[8];
            #pragma unroll
            for (int i = 0; i < 4; ++i) {
                int R = mblk + i * 16 + lr;
                af[i] = *reinterpret_cast<const i64*>(As + R * 128 + ((g ^ mix8(R)) << 4) + (lk & 1) * 8);
            }
            #pragma unroll
            for (int j = 0; j < 8; ++j) {
                int R = nblk + j * 16 + lr;
                bv[j] = *reinterpret_cast<const i64*>(Bs + R * 128 + ((g ^ mix8(R)) << 4) + (lk & 1) * 8);
            }
            #pragma unroll
            for (int i = 0; i < 4; ++i)
                #pragma unroll
                for (int j = 0; j < 8; ++j)
                    acc[i][j] = __builtin_amdgcn_mfma_f32_16x16x32_fp8_fp8(af[i], bv[j], acc[i][j], 0, 0, 0);
        }
    }

    const int lq = lane >> 4;
    float b2v[8];
    #pragma unroll
    for (int j = 0; j < 8; ++j) b2v[j] = b2[nblk + j * 16 + lr];
    // pass 1: per-row sumsq (wave-half partials)
    #pragma unroll
    for (int i = 0; i < 4; ++i)
        #pragma unroll
        for (int r = 0; r < 4; ++r) {
            float sq = 0.f;
            #pragma unroll
            for (int j = 0; j < 8; ++j) {
                float z = fmaf(acc[i][j][r], W1INV, b2v[j]);
                sq += z * z;
            }
            sq += __shfl_xor(sq, 1, 64);
            sq += __shfl_xor(sq, 2, 64);
            sq += __shfl_xor(sq, 4, 64);
            sq += __shfl_xor(sq, 8, 64);
            if (lr == 0) red[mblk + i * 16 + lq * 4 + r][wid & 1] = sq;
        }
    __syncthreads();
    // pass 2: normalize and write fp8
    #pragma unroll
    for (int i = 0; i < 4; ++i)
        #pragma unroll
        for (int r = 0; r < 4; ++r) {
            int rl = mblk + i * 16 + lq * 4 + r;
            float sq = red[rl][0] + red[rl][1];
            float inv = ZNSCALE / fmaxf(sqrtf(sq), COS_EPS);
            size_t rowbase = (size_t)(m0 + rl) * PROJ;
            #pragma unroll
            for (int j = 0; j < 8; ++j) {
                float z = fmaf(acc[i][j][r], W1INV, b2v[j]);
                ZNq[rowbase + nblk + j * 16 + lr] = f2fp8(z * inv);
            }
        }
}

// ---------------------------------------------------------------------------
// sim tiles (fp8), upper-triangle only, K=256 staged in ONE shot (1 barrier).
// Off-diag tiles contribute row AND column sums (bitwise-identical mirror).
// ---------------------------------------------------------------------------
__global__ __launch_bounds__(256) void simlse_fp8(
    const unsigned char* __restrict__ ZNq, float* __restrict__ rowsum,
    float* __restrict__ dgA, float* __restrict__ posA)
{
    if (blockIdx.x < blockIdx.y) return;   // symmetry: only tj >= ti
    __shared__ __align__(16) unsigned char As[128 * 256];
    __shared__ __align__(16) unsigned char Bs[128 * 256];
    const int tid = threadIdx.x;
    const int r0 = blockIdx.y * 128, j0 = blockIdx.x * 128;
    const bool offdiag = (j0 != r0);
    const unsigned char* Ab = ZNq + (size_t)r0 * PROJ;
    const unsigned char* Bb = ZNq + (size_t)j0 * PROJ;
    #pragma unroll
    for (int u = 0; u < 8; ++u) {
        int li = u * 256 + tid;
        int r = li >> 4, s = li & 15;
        gl_lds16(Ab + (size_t)r * PROJ + ((s ^ (r & 15)) * 16), As + li * 16);
    }
    #pragma unroll
    for (int u = 0; u < 8; ++u) {
        int li = u * 256 + tid;
        int r = li >> 4, s = li & 15;
        gl_lds16(Bb + (size_t)r * PROJ + ((s ^ (r & 15)) * 16), Bs + li * 16);
    }
    __syncthreads();
    const int wid = tid >> 6, lane = tid & 63;
    const int mblk = (wid >> 1) * 64, nblk = (wid & 1) * 64;
    const int lr = lane & 15, lk = lane >> 4;
    f32x4 zero = {0.f, 0.f, 0.f, 0.f};
    f32x4 acc[4][4];
    #pragma unroll
    for (int i = 0; i < 4; ++i)
        #pragma unroll
        for (int j = 0; j < 4; ++j) acc[i][j] = zero;
    #pragma unroll
    for (int t = 0; t < 8; ++t) {
        int g = 2 * t + (lk >> 1);
        i64 af[4], bv[4];
        #pragma unroll
        for (int i = 0; i < 4; ++i) {
            int R = mblk + i * 16 + lr;
            af[i] = *reinterpret_cast<const i64*>(As + R * 256 + ((g ^ (R & 15)) << 4) + (lk & 1) * 8);
        }
        #pragma unroll
        for (int j = 0; j < 4; ++j) {
            int R = nblk + j * 16 + lr;
            bv[j] = *reinterpret_cast<const i64*>(Bs + R * 256 + ((g ^ (R & 15)) << 4) + (lk & 1) * 8);
        }
        #pragma unroll
        for (int i = 0; i < 4; ++i)
            #pragma unroll
            for (int j = 0; j < 4; ++j)
                acc[i][j] = __builtin_amdgcn_mfma_f32_16x16x32_fp8_fp8(af[i], bv[j], acc[i][j], 0, 0, 0);
    }
    const int lq = lane >> 4;
    float tcol[4] = {0.f, 0.f, 0.f, 0.f};
    #pragma unroll
    for (int i = 0; i < 4; ++i)
        #pragma unroll
        for (int r = 0; r < 4; ++r) {
            int R = r0 + mblk + i * 16 + lq * 4 + r;
            int P = (R < BATCH) ? R + BATCH : R - BATCH;
            float t = 0.f;
            #pragma unroll
            for (int j = 0; j < 4; ++j) {
                int J = j0 + nblk + j * 16 + lr;
                float s = acc[i][j][r] * SIMSCALE;
                float e = __expf(s);
                t += e;
                tcol[j] += e;
                if (J == R) dgA[R] = e;                    // diag tiles only
                if (J == P) { posA[R] = s; posA[J] = s; }  // s[R,P]==s[P,R]
            }
            t += __shfl_xor(t, 1, 64);
            t += __shfl_xor(t, 2, 64);
            t += __shfl_xor(t, 4, 64);
            t += __shfl_xor(t, 8, 64);
            if (lr == 0) atomicAdd(&rowsum[R], t);
        }
    if (offdiag) {
        #pragma unroll
        for (int j = 0; j < 4; ++j) {
            float c = tcol[j];
            c += __shfl_xor(c, 16, 64);
            c += __shfl_xor(c, 32, 64);
            if (lq == 0) atomicAdd(&rowsum[j0 + nblk + j * 16 + lr], c);
        }
    }
}

// loss = (1/N) * sum_r [ log(rowsum_r - diag_r) - pos_r ]
__global__ __launch_bounds__(256) void loss_kernel(
    const float* __restrict__ rowsum, const float* __restrict__ dgA,
    const float* __restrict__ posA, float* __restrict__ out)
{
    __shared__ float red[256];
    float s = 0.f;
    for (int r = threadIdx.x; r < NROWS; r += 256)
        s += logf(rowsum[r] - dgA[r]) - posA[r];
    red[threadIdx.x] = s;
    __syncthreads();
    for (int off = 128; off > 0; off >>= 1) {
        if (threadIdx.x < off) red[threadIdx.x] += red[threadIdx.x + off];
        __syncthreads();
    }
    if (threadIdx.x == 0) out[0] = red[0] * (1.0f / NROWS);
}

// ---------------------------------------------------------------------------
extern "C" void kernel_launch(void* const* d_in, const int* in_sizes, int n_in,
                              void* d_out, int out_size, void* d_ws, size_t ws_size,
                              hipStream_t stream)
{
    const float* h_i   = (const float*)d_in[0];
    const float* h_j   = (const float*)d_in[1];
    const float* W1    = (const float*)d_in[2];
    const float* gamma = (const float*)d_in[3];
    const float* beta  = (const float*)d_in[4];
    const float* W2    = (const float*)d_in[5];
    const float* b2    = (const float*)d_in[6];
    float* out = (float*)d_out;

    // workspace (~23 MB)
    float* sums   = (float*)d_ws;                            // 4096
    float* sumsqs = sums + 2 * LATENT;                       // 4096
    float* rowsum = sumsqs + 2 * LATENT;                     // 4096
    float* dgA    = rowsum + NROWS;                          // 4096
    float* posA   = dgA + NROWS;                             // 4096
    unsigned char* Hq  = (unsigned char*)(posA + NROWS);     // 4096*2048 fp8
    unsigned char* W1q = Hq + (size_t)NROWS * LATENT;        // 2048*2048 fp8
    unsigned char* W2q = W1q + (size_t)LATENT * LATENT;      // 256*2048 fp8
    unsigned char* Xq  = W2q + (size_t)PROJ * LATENT;        // 4096*2048 fp8
    unsigned char* ZNq = Xq + (size_t)NROWS * LATENT;        // 4096*256 fp8

    cvt_all_kernel<<<(G4 + 255) / 256, 256, 0, stream>>>(h_i, h_j, W1, W2, Hq, W1q, W2q, sums);
    gemm1_fp8<<<dim3(LATENT / 64, NROWS / 128), 256, 0, stream>>>(Hq, W1q, Xq, sums, sumsqs);
    bnrelu8_kernel<<<NROWS, 256, 0, stream>>>(Xq, sums, sumsqs, gamma, beta);
    gemm2rn_fp8<<<NROWS / 128, 256, 0, stream>>>(Xq, W2q, b2, ZNq);
    simlse_fp8<<<dim3(NROWS / 128, NROWS / 128), 256, 0, stream>>>(ZNq, rowsum, dgA, posA);
    loss_kernel<<<1, 256, 0, stream>>>(rowsum, dgA, posA, out);
}